// Round 3
// baseline (441.395 us; speedup 1.0000x reference)
//
#include <hip/hip_runtime.h>

// Problem constants (setup_inputs: B=2, N=256, D=256, H=8, LEN=516)
#define NPAIR 131072   // B*N*N
#define NDIM  256      // D
#define NH    8        // heads
#define NN    256      // N (k-dimension for topk / ind)
#define NROWS 512      // B*N rows for topk
#define LEN   516      // 2*D + 4
#define EPSV  1e-8f

__device__ __forceinline__ float dot4(float4 a, float4 b) {
    return fmaf(a.x, b.x, fmaf(a.y, b.y, fmaf(a.z, b.z, a.w * b.w)));
}

// Kernel 1: one LANE per (b,q,k) pair. 4 waves/block, each wave owns 64
// consecutive pairs and a PRIVATE 8 KB LDS region (no inter-wave sync).
// Per 16-dim chunk: coalesced global->reg prefetch, reg->LDS (swizzled),
// LDS->reg transpose (lane = pair), FMA chains. W operands are wave-uniform
// -> scalar loads. No cross-lane reductions anywhere.
// Chunk arrays kept at 4 float4 each so everything stays in ~100 VGPRs
// (round 2's 8-float4 arrays spilled to scratch: 264 MB of WRITE_SIZE).
__global__ __launch_bounds__(256, 4) void fused_main(
    const float* __restrict__ Q, const float* __restrict__ K,
    const float* __restrict__ SQ, const float* __restrict__ SK,
    const float* __restrict__ ROI, const float* __restrict__ W,
    const float* __restrict__ Bb, float* __restrict__ out,
    float* __restrict__ scores)
{
    __shared__ float4 lds[4][2][256];     // [wave][Q/K][64 rows x 4 f4] 32 KB

    const int tid  = threadIdx.x;
    const int w    = tid >> 6;
    const int lane = tid & 63;
    const int p0   = blockIdx.x * 256 + w * 64;   // wave's first pair
    const int rlo  = lane >> 2;          // staging row within group (0..15)
    const int jc   = lane & 3;           // staging f4 column (0..3)

    float4* Qb = lds[w][0];
    float4* Kb = lds[w][1];
    const float4* Q4 = (const float4*)Q;   // pair p = f4 [p*64, p*64+64)
    const float4* K4 = (const float4*)K;

    // acc[0..7] = q.Wq_h + k.Wk_h ; acc[8]=q.k ; acc[9]=q.q ; acc[10]=k.k
    float acc[11];
#pragma unroll
    for (int i = 0; i < 11; ++i) acc[i] = 0.0f;

    // Prefetch chunk 0: 4 instrs/operand, each 16 rows x 64 B segments.
    float4 gq[4], gk[4];
#pragma unroll
    for (int t = 0; t < 4; ++t) {
        const size_t g = (size_t)(p0 + 16 * t + rlo) * 64 + jc;
        gq[t] = Q4[g];
        gk[t] = K4[g];
    }

    for (int c = 0; c < 16; ++c) {
        // Stage chunk c into this wave's LDS region (XOR-swizzled cols).
#pragma unroll
        for (int t = 0; t < 4; ++t) {
            const int row = 16 * t + rlo;
            const int idx = row * 4 + (jc ^ ((row >> 2) & 3));
            Qb[idx] = gq[t];
            Kb[idx] = gk[t];
        }
        if (c < 15) {                    // prefetch next chunk
#pragma unroll
            for (int t = 0; t < 4; ++t) {
                const size_t g = (size_t)(p0 + 16 * t + rlo) * 64
                               + (c + 1) * 4 + jc;
                gq[t] = Q4[g];
                gk[t] = K4[g];
            }
        }
        __builtin_amdgcn_wave_barrier();  // wave-synchronous LDS: no reorder

        // Transpose read: lane reads its own pair's 16-dim chunk.
        float4 qc[4], kc[4];
#pragma unroll
        for (int j = 0; j < 4; ++j) {
            const int idx = lane * 4 + (j ^ ((lane >> 2) & 3));
            qc[j] = Qb[idx];
            kc[j] = Kb[idx];
        }
        __builtin_amdgcn_wave_barrier();  // reads before next chunk's writes

        // Cosine partials (3 independent chains).
#pragma unroll
        for (int j = 0; j < 4; ++j) {
            acc[8]  += dot4(qc[j], kc[j]);
            acc[9]  += dot4(qc[j], qc[j]);
            acc[10] += dot4(kc[j], kc[j]);
        }
        // Head projections; W addresses wave-uniform -> scalar loads.
#pragma unroll
        for (int h = 0; h < NH; ++h) {
            const float4* wq = (const float4*)(W + h * LEN + c * 16);
            const float4* wk = (const float4*)(W + h * LEN + 256 + c * 16);
            float a0 = 0.0f;
#pragma unroll
            for (int j = 0; j < 4; ++j) {
                a0 += dot4(qc[j], wq[j]);
                a0 += dot4(kc[j], wk[j]);
            }
            acc[h] += a0;
        }
    }

    // Epilogue: lane's pair p = p0 + lane. All stores coalesced.
    const int p = p0 + lane;
    const float qn = fmaxf(sqrtf(acc[9]),  EPSV);
    const float kn = fmaxf(sqrtf(acc[10]), EPSV);
    scores[p] = fmaxf(acc[8] / (qn * kn), 0.0f);

    const float2 sq = ((const float2*)SQ)[p];
    const float2 sk = ((const float2*)SK)[p];
    const float roi = ROI[p];
    float ov[NH];
#pragma unroll
    for (int h = 0; h < NH; ++h) {
        const float4 wt = *(const float4*)(W + h * LEN + 512);  // uniform
        float x = acc[h] + sq.x * wt.x + sq.y * wt.y
                         + sk.x * wt.z + sk.y * wt.w + Bb[h];
        ov[h] = roi / (1.0f + __expf(-x));
    }
    ((float4*)out)[(size_t)p * 2]     = make_float4(ov[0], ov[1], ov[2], ov[3]);
    ((float4*)out)[(size_t)p * 2 + 1] = make_float4(ov[4], ov[5], ov[6], ov[7]);
}

// Kernel 2: zero the indicator (ws is poisoned 0xAA before each launch).
__global__ void zero_ind(float* __restrict__ ind) {
    ind[threadIdx.x] = 0.0f;
}

// Kernel 3: per (b,q) row, extract top-k indices (stable: ties -> lower
// index) and mark ind[idx] = 1.0. One wave per row.
__global__ __launch_bounds__(64) void topk_kernel(
    const float* __restrict__ scores, float* __restrict__ ind,
    const int* __restrict__ node_num)
{
    const int row = blockIdx.x;
    const int lane = threadIdx.x;
    const float4 v4 = *(const float4*)(scores + row * NN + lane * 4);
    float v[4] = {v4.x, v4.y, v4.z, v4.w};

    int Kk = node_num[0];
    if (Kk > NN) Kk = NN;
    for (int t = 0; t < Kk; t++) {
        float mv = v[0];
        int mi = lane * 4;
#pragma unroll
        for (int j = 1; j < 4; j++) {
            if (v[j] > mv) { mv = v[j]; mi = lane * 4 + j; }
        }
        for (int off = 32; off > 0; off >>= 1) {
            const float ov = __shfl_xor(mv, off, 64);
            const int   oi = __shfl_xor(mi, off, 64);
            if (ov > mv || (ov == mv && oi < mi)) { mv = ov; mi = oi; }
        }
        if (lane == 0) ind[mi] = 1.0f;             // idempotent 1.0 store
        if ((mi >> 2) == lane) v[mi & 3] = -1.0f;  // remove (scores >= 0)
    }
}

// Kernel 4: out *= ind[k]; float4 over out (element e: k = (e/8)%256).
__global__ __launch_bounds__(256) void apply_ind_kernel(
    float* __restrict__ out, const float* __restrict__ ind)
{
    const int i = blockIdx.x * blockDim.x + threadIdx.x;  // float4 index
    float4 v = ((float4*)out)[i];
    const float m = ind[(i >> 1) & (NN - 1)];
    v.x *= m; v.y *= m; v.z *= m; v.w *= m;
    ((float4*)out)[i] = v;
}

extern "C" void kernel_launch(void* const* d_in, const int* in_sizes, int n_in,
                              void* d_out, int out_size, void* d_ws, size_t ws_size,
                              hipStream_t stream)
{
    const float* Q   = (const float*)d_in[0];
    const float* K   = (const float*)d_in[1];
    const float* SQ  = (const float*)d_in[2];
    const float* SK  = (const float*)d_in[3];
    const float* ROI = (const float*)d_in[4];
    const float* W   = (const float*)d_in[5];
    const float* Bb  = (const float*)d_in[6];
    const int* node_num = (const int*)d_in[7];

    float* out = (float*)d_out;
    float* scores = (float*)d_ws;          // NPAIR floats (512 KB)
    float* ind = scores + NPAIR;           // NN floats

    fused_main<<<NPAIR / 256, 256, 0, stream>>>(Q, K, SQ, SK, ROI, W, Bb, out, scores);
    zero_ind<<<1, 256, 0, stream>>>(ind);
    topk_kernel<<<NROWS, 64, 0, stream>>>(scores, ind, node_num);
    apply_ind_kernel<<<out_size / 4 / 256, 256, 0, stream>>>(out, ind);
}

// Round 4
// 322.018 us; speedup vs baseline: 1.3707x; 1.3707x over previous
//
#include <hip/hip_runtime.h>

// Problem constants (setup_inputs: B=2, N=256, D=256, H=8, LEN=516)
#define NPAIR 131072   // B*N*N
#define NDIM  256      // D
#define NH    8        // heads
#define NN    256      // N (k-dimension for topk / ind)
#define NROWS 512      // B*N rows for topk
#define LEN   516      // 2*D + 4
#define EPSV  1e-8f

__device__ __forceinline__ float dot4(float4 a, float4 b) {
    return fmaf(a.x, b.x, fmaf(a.y, b.y, fmaf(a.z, b.z, a.w * b.w)));
}

// DPP add step: x += dpp_shifted(x); invalid source lanes contribute 0.
#define DPP_ADD(x, ctrl)                                                        \
    x += __int_as_float(__builtin_amdgcn_update_dpp(                            \
        0, __float_as_int(x), (ctrl), 0xf, 0xf, false))

// Wave64 sum via DPP (VALU only). Total lands in lane 63 (verified round 1).
__device__ __forceinline__ float wave_sum63(float x) {
    DPP_ADD(x, 0x111);  // row_shr:1
    DPP_ADD(x, 0x112);  // row_shr:2
    DPP_ADD(x, 0x114);  // row_shr:4
    DPP_ADD(x, 0x118);  // row_shr:8  -> lane 15 of each row = row sum
    DPP_ADD(x, 0x142);  // row_bcast:15 -> lane31 = r0+r1, lane63 = r2+r3
    DPP_ADD(x, 0x143);  // row_bcast:31 -> lane63 = total
    return x;           // only lane 63 holds the full sum
}

// Kernel 1: one WAVE per (b,q,k) pair (round-1 structure: proven no-spill).
// Lanes cover D (4 floats each), coalesced 1 KB float4 loads.
// 11 reductions/pair (q&k head projections combined pre-reduction), DPP only.
// Head totals fan out via v_readlane -> SGPR -> cndmask; lanes 0-7 store out.
__global__ __launch_bounds__(256, 4) void fused_main(
    const float* __restrict__ Q, const float* __restrict__ K,
    const float* __restrict__ SQ, const float* __restrict__ SK,
    const float* __restrict__ ROI, const float* __restrict__ W,
    const float* __restrict__ Bb, float* __restrict__ out,
    float* __restrict__ scores)
{
    const int lane = threadIdx.x & 63;
    const int h = lane & 7;
    const int nwaves = (gridDim.x * blockDim.x) >> 6;
    const int wave = (blockIdx.x * blockDim.x + threadIdx.x) >> 6;

    const float4* __restrict__ Q4 = (const float4*)Q;  // pair p = f4 [p*64, p*64+64)
    const float4* __restrict__ K4 = (const float4*)K;

    // W cache: lane holds W[i][4*lane..4*lane+3] (q half) and the k half,
    // all 8 heads -> 64 VGPRs. If the allocator remats these, they're L1 hits.
    float4 wq[NH], wk[NH];
#pragma unroll
    for (int i = 0; i < NH; i++) {
        wq[i] = *(const float4*)(W + i * LEN + lane * 4);
        wk[i] = *(const float4*)(W + i * LEN + 256 + lane * 4);
    }
    // Spatial tail + bias for this lane's head (lane&7): per-lane, loop-invariant.
    const float4 wt = *(const float4*)(W + h * LEN + 512);
    const float bh = Bb[h];

    for (int p0 = wave; p0 < NPAIR; p0 += nwaves) {
        const int p = __builtin_amdgcn_readfirstlane(p0);
        const float4 qv = Q4[(size_t)p * 64 + lane];
        const float4 kv = K4[(size_t)p * 64 + lane];

        // r[0..7] = per-lane partial of q.Wq_h + k.Wk_h (combined BEFORE
        // reduction: 11 reductions, not 19). r[8]=q.k r[9]=q.q r[10]=k.k.
        float r[11];
        r[8]  = dot4(qv, kv);
        r[9]  = dot4(qv, qv);
        r[10] = dot4(kv, kv);
#pragma unroll
        for (int i = 0; i < NH; i++)
            r[i] = dot4(qv, wq[i]) + dot4(kv, wk[i]);

#pragma unroll
        for (int i = 0; i < 11; i++)
            r[i] = wave_sum63(r[i]);   // totals valid in lane 63

        // Cosine score: lane 63 owns r[8..10].
        if (lane == 63) {
            const float qn = fmaxf(sqrtf(r[9]),  EPSV);
            const float kn = fmaxf(sqrtf(r[10]), EPSV);
            scores[p] = fmaxf(r[8] / (qn * kn), 0.0f);
        }

        // Head totals: lane63 -> SGPR -> every lane picks its head's value.
        float hs = 0.0f;
#pragma unroll
        for (int i = 0; i < NH; i++) {
            const float si = __int_as_float(
                __builtin_amdgcn_readlane(__float_as_int(r[i]), 63));
            hs = (h == i) ? si : hs;
        }

        // Spatial terms (wave-uniform addresses -> scalar loads) + sigmoid.
        const float2 sq = ((const float2*)SQ)[p];
        const float2 sk = ((const float2*)SK)[p];
        const float roi = ROI[p];
        const float x = hs + sq.x * wt.x + sq.y * wt.y
                           + sk.x * wt.z + sk.y * wt.w + bh;
        const float y = roi / (1.0f + __expf(-x));
        if (lane < NH) out[(size_t)p * NH + lane] = y;  // 32 B coalesced
    }
}

// Kernel 2: zero the indicator (ws is poisoned 0xAA before each launch).
__global__ void zero_ind(float* __restrict__ ind) {
    ind[threadIdx.x] = 0.0f;
}

// Kernel 3: per (b,q) row, extract top-k indices (stable: ties -> lower
// index) and mark ind[idx] = 1.0. One wave per row.
__global__ __launch_bounds__(64) void topk_kernel(
    const float* __restrict__ scores, float* __restrict__ ind,
    const int* __restrict__ node_num)
{
    const int row = blockIdx.x;
    const int lane = threadIdx.x;
    const float4 v4 = *(const float4*)(scores + row * NN + lane * 4);
    float v[4] = {v4.x, v4.y, v4.z, v4.w};

    int Kk = node_num[0];
    if (Kk > NN) Kk = NN;
    for (int t = 0; t < Kk; t++) {
        float mv = v[0];
        int mi = lane * 4;
#pragma unroll
        for (int j = 1; j < 4; j++) {
            if (v[j] > mv) { mv = v[j]; mi = lane * 4 + j; }
        }
        for (int off = 32; off > 0; off >>= 1) {
            const float ov = __shfl_xor(mv, off, 64);
            const int   oi = __shfl_xor(mi, off, 64);
            if (ov > mv || (ov == mv && oi < mi)) { mv = ov; mi = oi; }
        }
        if (lane == 0) ind[mi] = 1.0f;             // idempotent 1.0 store
        if ((mi >> 2) == lane) v[mi & 3] = -1.0f;  // remove (scores >= 0)
    }
}

// Kernel 4: out *= ind[k]; float4 over out (element e: k = (e/8)%256).
__global__ __launch_bounds__(256) void apply_ind_kernel(
    float* __restrict__ out, const float* __restrict__ ind)
{
    const int i = blockIdx.x * blockDim.x + threadIdx.x;  // float4 index
    float4 v = ((float4*)out)[i];
    const float m = ind[(i >> 1) & (NN - 1)];
    v.x *= m; v.y *= m; v.z *= m; v.w *= m;
    ((float4*)out)[i] = v;
}

extern "C" void kernel_launch(void* const* d_in, const int* in_sizes, int n_in,
                              void* d_out, int out_size, void* d_ws, size_t ws_size,
                              hipStream_t stream)
{
    const float* Q   = (const float*)d_in[0];
    const float* K   = (const float*)d_in[1];
    const float* SQ  = (const float*)d_in[2];
    const float* SK  = (const float*)d_in[3];
    const float* ROI = (const float*)d_in[4];
    const float* W   = (const float*)d_in[5];
    const float* Bb  = (const float*)d_in[6];
    const int* node_num = (const int*)d_in[7];

    float* out = (float*)d_out;
    float* scores = (float*)d_ws;          // NPAIR floats (512 KB)
    float* ind = scores + NPAIR;           // NN floats

    fused_main<<<2048, 256, 0, stream>>>(Q, K, SQ, SK, ROI, W, Bb, out, scores);
    zero_ind<<<1, 256, 0, stream>>>(ind);
    topk_kernel<<<NROWS, 64, 0, stream>>>(scores, ind, node_num);
    apply_ind_kernel<<<out_size / 4 / 256, 256, 0, stream>>>(out, ind);
}

// Round 5
// 320.005 us; speedup vs baseline: 1.3793x; 1.0063x over previous
//
#include <hip/hip_runtime.h>
#include <hip/hip_bf16.h>

// Problem constants (setup_inputs: B=2, N=256, D=256, H=8, LEN=516)
#define NPAIR 131072   // B*N*N
#define NUNIT 8192     // NPAIR / 16 pairs per MFMA tile
#define NH    8        // heads
#define NN    256      // N (k-dimension for topk / ind)
#define NROWS 512      // B*N rows for topk
#define LEN   516      // 2*D + 4
#define EPSV  1e-8f

typedef __attribute__((ext_vector_type(8))) short bf16x8;  // MFMA A/B frag
typedef __attribute__((ext_vector_type(4))) float f32x4;   // MFMA C/D frag

__device__ __forceinline__ unsigned int pk2(float x, float y) {
    union { __hip_bfloat162 h; unsigned int u; } c;
    c.h = __float22bfloat162_rn(make_float2(x, y));
    return c.u;   // low 16 = x, high 16 = y
}
__device__ __forceinline__ bf16x8 pack8(float4 a, float4 b) {
    union { unsigned int u[4]; bf16x8 v; } r;
    r.u[0] = pk2(a.x, a.y);
    r.u[1] = pk2(a.z, a.w);
    r.u[2] = pk2(b.x, b.y);
    r.u[3] = pk2(b.z, b.w);
    return r.v;
}

// Kernel 1: one 16x16x32 MFMA tile block per 16 consecutive pairs.
// A-frag and B-frag share the same lane->element map (lane l holds
// row/col m=l&15, k=(l>>4)*8+j), so Q-row frags and K-row frags are loaded
// ONCE and reused:  mfma(Qf,Kf)=Q@K^T (diag=q.k), mfma(Qf,Qf) diag=|q|^2,
// mfma(Kf,Kf) diag=|k|^2, mfma(Qf,Wq)+mfma(Kf,Wk)=head projections.
// Zero cross-lane reductions, zero LDS. (DPP-reduction structure measured
// at ~530 issued instrs/pair in r1/r4; this is ~25.)
// No __launch_bounds__ min-occupancy: r2/r3 showed occupancy-capped
// allocation provokes scratch spill (WRITE_SIZE 199-264 MB).
__global__ void fused_main(
    const float* __restrict__ Q, const float* __restrict__ K,
    const float* __restrict__ SQ, const float* __restrict__ SK,
    const float* __restrict__ ROI, const float* __restrict__ W,
    const float* __restrict__ Bb, float* __restrict__ out,
    float* __restrict__ scores)
{
    const int l    = threadIdx.x & 63;
    const int quad = l >> 4;        // 0..3
    const int m    = l & 15;        // tile row (pairs) / tile col (heads)
    const int hh   = m & 7;         // W row for this lane's output column
    const int koff = quad * 8;      // k-offset within a 32-wide chunk
    const int nwaves = (gridDim.x * blockDim.x) >> 6;
    const int wave = (blockIdx.x * blockDim.x + threadIdx.x) >> 6;

    // W fragments (persistent): B-frag for chunk c holds
    // W[col][c*32 + koff + j].  q-half and k-half separately.
    bf16x8 wqf[8], wkf[8];
#pragma unroll
    for (int c = 0; c < 8; ++c) {
        const float* wp = W + hh * LEN + c * 32 + koff;
        wqf[c] = pack8(*(const float4*)wp,        *(const float4*)(wp + 4));
        wkf[c] = pack8(*(const float4*)(wp + 256), *(const float4*)(wp + 260));
    }
    // Spatial tail + bias for this lane's head column (hoisted).
    const float4 wt = *(const float4*)(W + hh * LEN + 512);
    const float bh = Bb[hh];

    const bool diag_owner = ((m >> 2) == quad);   // owns diag element m
    const int  dreg = m & 3;

    for (int u = wave; u < NUNIT; u += nwaves) {
        const int p0 = u * 16;
        const float* qbase = Q + (size_t)(p0 + m) * 256 + koff;
        const float* kbase = K + (size_t)(p0 + m) * 256 + koff;

        f32x4 a_qk = {0.f, 0.f, 0.f, 0.f};
        f32x4 a_qq = {0.f, 0.f, 0.f, 0.f};
        f32x4 a_kk = {0.f, 0.f, 0.f, 0.f};
        f32x4 a_pr = {0.f, 0.f, 0.f, 0.f};

#pragma unroll
        for (int c = 0; c < 8; ++c) {
            const float4 qa = *(const float4*)(qbase + c * 32);
            const float4 qb = *(const float4*)(qbase + c * 32 + 4);
            const float4 ka = *(const float4*)(kbase + c * 32);
            const float4 kb = *(const float4*)(kbase + c * 32 + 4);
            const bf16x8 qf = pack8(qa, qb);
            const bf16x8 kf = pack8(ka, kb);
            a_qk = __builtin_amdgcn_mfma_f32_16x16x32_bf16(qf, kf, a_qk, 0, 0, 0);
            a_qq = __builtin_amdgcn_mfma_f32_16x16x32_bf16(qf, qf, a_qq, 0, 0, 0);
            a_kk = __builtin_amdgcn_mfma_f32_16x16x32_bf16(kf, kf, a_kk, 0, 0, 0);
            a_pr = __builtin_amdgcn_mfma_f32_16x16x32_bf16(qf, wqf[c], a_pr, 0, 0, 0);
            a_pr = __builtin_amdgcn_mfma_f32_16x16x32_bf16(kf, wkf[c], a_pr, 0, 0, 0);
        }

        // Cosine scores: diag elements of qk/qq/kk tiles.
        if (diag_owner) {
            const float qk = a_qk[dreg];
            const float qq = a_qq[dreg];
            const float kk = a_kk[dreg];
            const float d = fmaxf(sqrtf(qq), EPSV) * fmaxf(sqrtf(kk), EPSV);
            scores[p0 + m] = fmaxf(qk / d, 0.0f);
        }

        // Projection epilogue: lane's column h = m (<8 valid); 4 rows.
        if (m < NH) {
#pragma unroll
            for (int r = 0; r < 4; ++r) {
                const int p = p0 + quad * 4 + r;
                const float2 sq = ((const float2*)SQ)[p];
                const float2 sk = ((const float2*)SK)[p];
                const float roi = ROI[p];
                const float x = a_pr[r] + sq.x * wt.x + sq.y * wt.y
                                        + sk.x * wt.z + sk.y * wt.w + bh;
                out[(size_t)p * NH + m] = roi / (1.0f + __expf(-x));
            }
        }
    }
}

// Kernel 2: zero the indicator (ws is poisoned 0xAA before each launch).
__global__ void zero_ind(float* __restrict__ ind) {
    ind[threadIdx.x] = 0.0f;
}

// Kernel 3: per (b,q) row, extract top-k indices (stable: ties -> lower
// index) and mark ind[idx] = 1.0. One wave per row.
__global__ __launch_bounds__(64) void topk_kernel(
    const float* __restrict__ scores, float* __restrict__ ind,
    const int* __restrict__ node_num)
{
    const int row = blockIdx.x;
    const int lane = threadIdx.x;
    const float4 v4 = *(const float4*)(scores + row * NN + lane * 4);
    float v[4] = {v4.x, v4.y, v4.z, v4.w};

    int Kk = node_num[0];
    if (Kk > NN) Kk = NN;
    for (int t = 0; t < Kk; t++) {
        float mv = v[0];
        int mi = lane * 4;
#pragma unroll
        for (int j = 1; j < 4; j++) {
            if (v[j] > mv) { mv = v[j]; mi = lane * 4 + j; }
        }
        for (int off = 32; off > 0; off >>= 1) {
            const float ov = __shfl_xor(mv, off, 64);
            const int   oi = __shfl_xor(mi, off, 64);
            if (ov > mv || (ov == mv && oi < mi)) { mv = ov; mi = oi; }
        }
        if (lane == 0) ind[mi] = 1.0f;             // idempotent 1.0 store
        if ((mi >> 2) == lane) v[mi & 3] = -1.0f;  // remove (scores >= 0)
    }
}

// Kernel 4: out *= ind[k]; float4 over out (element e: k = (e/8)%256).
__global__ __launch_bounds__(256) void apply_ind_kernel(
    float* __restrict__ out, const float* __restrict__ ind)
{
    const int i = blockIdx.x * blockDim.x + threadIdx.x;  // float4 index
    float4 v = ((float4*)out)[i];
    const float m = ind[(i >> 1) & (NN - 1)];
    v.x *= m; v.y *= m; v.z *= m; v.w *= m;
    ((float4*)out)[i] = v;
}

extern "C" void kernel_launch(void* const* d_in, const int* in_sizes, int n_in,
                              void* d_out, int out_size, void* d_ws, size_t ws_size,
                              hipStream_t stream)
{
    const float* Q   = (const float*)d_in[0];
    const float* K   = (const float*)d_in[1];
    const float* SQ  = (const float*)d_in[2];
    const float* SK  = (const float*)d_in[3];
    const float* ROI = (const float*)d_in[4];
    const float* W   = (const float*)d_in[5];
    const float* Bb  = (const float*)d_in[6];
    const int* node_num = (const int*)d_in[7];

    float* out = (float*)d_out;
    float* scores = (float*)d_ws;          // NPAIR floats (512 KB)
    float* ind = scores + NPAIR;           // NN floats

    fused_main<<<1024, 256, 0, stream>>>(Q, K, SQ, SK, ROI, W, Bb, out, scores);
    zero_ind<<<1, 256, 0, stream>>>(ind);
    topk_kernel<<<NROWS, 64, 0, stream>>>(scores, ind, node_num);
    apply_ind_kernel<<<out_size / 4 / 256, 256, 0, stream>>>(out, ind);
}